// Round 8
// baseline (218.179 us; speedup 1.0000x reference)
//
#include <hip/hip_runtime.h>

// NONA: out = softmax(-cdist(x, x_n), axis=1) @ y
//   x[4096,1024] f32, x_n[8192,1024] f32, y[8192,128] f32, log_T unused.
//
// R8 (R7 measured: coarse 1-phase counted-vmcnt loop = 616 TF regardless of
// geometry; pv/W overhead 90 us):
//  * re-fused single main kernel: 256-row x 512-col blocks (two 256^2 S-tiles),
//    P round-trips through LDS, O accumulates in regs across both tiles,
//    partials Opart[16][N][C] (32 MiB) + Lpart[16][N]; combine kernel divides.
//  * 4-phase K-step (m201-style T3+T4): per phase
//      vmcnt(4); s_barrier; sched_barrier(0); issue 2 half-operand loads
//      (next step); ds_read quadrant frags; setprio(1); 16 MFMA; setprio(0)
//    Loads chunk-mapped so phase p's loads = exactly the operand-half that
//    phase p consumes NEXT step (>=2 phases of flight, uniform vmcnt(4)).
//    WAR: issue is after the phase barrier that retires prev-step reads.
//    RAW: vmcnt(4)+barrier => the 2 required load-pairs (issued >=2 phases
//    ago) have landed across all waves. kk=15 peeled: vmcnt(4/2/0/0), no issue.
//  * quadrant order (rh,ch) = (0,0),(0,1),(1,1),(1,0): af reused across
//    (p0,p1) and (p2,p3), bv ch1 reused across (p1,p2) -> 28 reads/step.
//  * epilogue per tile: seal; stage yT halves -> A0/B1 (fly under exp);
//    P-h0 -> A1+B0; sync; PV-h0; sync; P-h1; sync; PV-h1; sync.
//
// ws: xb@0 8Mi | xnb@8Mi 16Mi | yT@24Mi 2Mi | xsq@26Mi 16Ki | xnsq +16Ki |
//     l +48Ki | Lpart@26Mi+64Ki 256Ki | Opart@27Mi 32Mi  (total 59Mi <= 62 known)

#define N_ 4096
#define M_ 8192
#define D_ 1024
#define C_ 128
#define NKK 16
#define NCBG 16

typedef __bf16 bf16;
typedef __attribute__((ext_vector_type(8))) __bf16 bf16x8;
typedef __attribute__((ext_vector_type(4))) __bf16 bf16x4;
typedef __attribute__((ext_vector_type(4))) float f32x4;

__device__ __forceinline__ void async_copy16(const bf16* gp, void* lp) {
  __builtin_amdgcn_global_load_lds(
      (__attribute__((address_space(1))) void*)const_cast<bf16*>(gp),
      (__attribute__((address_space(3))) void*)lp, 16, 0, 0);
}

// 128-B-row tiles (A/B): granule(16B) XOR row&7 (proven 0-conflict R1-R7)
__device__ __forceinline__ int swz(int row, int gran) {
  return (row << 7) + ((gran ^ (row & 7)) << 4);
}
// 256-B-row tiles (P / yT): 16 granules, XOR row&15
__device__ __forceinline__ int swz2(int row, int gran) {
  return (row << 8) + ((gran ^ (row & 15)) << 4);
}

// A-half: rows [wr*128+rh*64, +64) of a [256][64] tile = chunks {rh*8+w, 16+rh*8+w}
__device__ __forceinline__ void stageAh(const bf16* src, char* lds, int rh, int tid) {
  const int lane = tid & 63, wave = tid >> 6;
#pragma unroll
  for (int jj = 0; jj < 2; ++jj) {
    const int ch  = jj * 16 + rh * 8 + wave;
    const int off = ch * 1024 + lane * 16;
    const int row = off >> 7;
    const int gr  = ((off >> 4) & 7) ^ (row & 7);
    async_copy16(src + (size_t)row * D_ + gr * 8, lds + ch * 1024);
  }
}
// B-half ch: rows wc*64+ch*32..+32 for all wc = chunks {band*8 + ch*4 + 0..3}
__device__ __forceinline__ void stageBh(const bf16* src, char* lds, int chh, int tid) {
  const int lane = tid & 63, wave = tid >> 6;
#pragma unroll
  for (int jj = 0; jj < 2; ++jj) {
    const int ch  = ((wave >> 1) << 3) + chh * 4 + ((wave & 1) << 1) + jj;
    const int off = ch * 1024 + lane * 16;
    const int row = off >> 7;
    const int gr  = ((off >> 4) & 7) ^ (row & 7);
    async_copy16(src + (size_t)row * D_ + gr * 8, lds + ch * 1024);
  }
}
// yT half h: [128 C][128 xn] bf16, 256-B rows, 32 KiB
__device__ __forceinline__ void stageV(const bf16* yT, int colbase, int h, char* lds, int tid) {
  const int lane = tid & 63, wave = tid >> 6;
#pragma unroll
  for (int jj = 0; jj < 4; ++jj) {
    const int ch  = jj * 8 + wave;
    const int off = ch * 1024 + lane * 16;
    const int row = off >> 8;
    const int gr  = ((off >> 4) & 15) ^ (row & 15);
    async_copy16(yT + (size_t)row * M_ + colbase + h * 128 + gr * 8, lds + ch * 1024);
  }
}

#define RD_AF(Ac, RH)                                                          \
  _Pragma("unroll") for (int ks = 0; ks < 2; ++ks)                             \
  _Pragma("unroll") for (int i = 0; i < 4; ++i)                                \
    af[i][ks] = *(const bf16x8*)((Ac) + swz(wr * 128 + ((RH)*4 + i) * 16 + c, ks * 4 + g));
#define RD_BV(Bc, CH)                                                          \
  _Pragma("unroll") for (int ks = 0; ks < 2; ++ks)                             \
  _Pragma("unroll") for (int j = 0; j < 2; ++j)                                \
    bv[j][ks] = *(const bf16x8*)((Bc) + swz(wc * 64 + ((CH)*2 + j) * 16 + c, ks * 4 + g));
// swapped-S: Sacc = mfma(A=xn_frag, B=x_frag) -> lane holds
// S[xn = wc*64+cf*16+g*4+r][x = wr*128+rf*16+c]
#define QMFMA(RH, CH)                                                          \
  __builtin_amdgcn_s_setprio(1);                                               \
  _Pragma("unroll") for (int ks = 0; ks < 2; ++ks)                             \
  _Pragma("unroll") for (int j = 0; j < 2; ++j)                                \
  _Pragma("unroll") for (int i = 0; i < 4; ++i)                                \
    Sacc[(RH)*4 + i][(CH)*2 + j] = __builtin_amdgcn_mfma_f32_16x16x32_bf16(    \
        bv[j][ks], af[i][ks], Sacc[(RH)*4 + i][(CH)*2 + j], 0, 0, 0);          \
  __builtin_amdgcn_s_setprio(0);
#define PH_SYNC(VM)                                                            \
  asm volatile("s_waitcnt vmcnt(" #VM ")" ::: "memory");                       \
  __builtin_amdgcn_s_barrier();                                                \
  __builtin_amdgcn_sched_barrier(0);

__global__ __launch_bounds__(512, 2)
void nona_main(const bf16* __restrict__ xb, const bf16* __restrict__ xnb,
               const bf16* __restrict__ yT, const float* __restrict__ xsq,
               const float* __restrict__ xnsq, float* __restrict__ Opart,
               float* __restrict__ Lpart)
{
  __shared__ __align__(16) char Lds[131072];
  char* const A0 = Lds;            // x [256][64] even kk; tail: yT-h0 [128][128]
  char* const A1 = Lds + 32768;    // x [256][64] odd kk;  tail: P (with B0)
  char* const B0 = Lds + 65536;    // xn [256][64] even kk; tail: P (with A1)
  char* const B1 = Lds + 98304;    // xn [256][64] odd kk;  tail: yT-h1
  char* const Pb = Lds + 32768;    // P [256 x][128 xn], 256-B rows, 64 KiB

  const int tid  = threadIdx.x;
  const int lane = tid & 63;
  const int wave = tid >> 6;           // 8 waves: wr(2) x wc(4)
  const int wr = wave >> 2, wc = wave & 3;
  const int g = lane >> 4, c = lane & 15;

  const int cbg = blockIdx.x & 15;     // bid%8 = cbg%8 -> XCD-pinned col group
  const int rb  = blockIdx.x >> 4;
  const int row0 = rb * 256;

  f32x4 Oacc[2][8];
  const f32x4 zero = {0.f, 0.f, 0.f, 0.f};
#pragma unroll
  for (int rf = 0; rf < 2; ++rf)
#pragma unroll
    for (int cc = 0; cc < 8; ++cc) Oacc[rf][cc] = zero;
  float lsum[8] = {};

  const bf16* xA = xb + (size_t)row0 * D_;

  auto writeP = [&](f32x4 (&S)[8][4]) {   // write this wave's Sacc into P (its xn half)
#pragma unroll
    for (int rf = 0; rf < 8; ++rf)
#pragma unroll
      for (int cf = 0; cf < 4; ++cf) {
        bf16x4 pk;
#pragma unroll
        for (int r = 0; r < 4; ++r) pk[r] = (bf16)S[rf][cf][r];
        const int row  = wr * 128 + rf * 16 + c;
        const int gran = (wc & 1) * 8 + cf * 2 + (g >> 1);
        *(bf16x4*)(Pb + (row << 8) + ((gran ^ (row & 15)) << 4) + (g & 1) * 8) = pk;
      }
  };
  auto pvHalf = [&](const char* Vb) {     // Oacc += P_half @ V_half^T
#pragma unroll
    for (int ks = 0; ks < 4; ++ks) {
      bf16x8 pa[2];
#pragma unroll
      for (int rf = 0; rf < 2; ++rf) {
        const int row = wave * 32 + rf * 16 + c;
        pa[rf] = *(const bf16x8*)(Pb + swz2(row, ks * 4 + g));
      }
      __builtin_amdgcn_s_setprio(1);
#pragma unroll
      for (int cc = 0; cc < 8; ++cc) {
        bf16x8 vb = *(const bf16x8*)(Vb + swz2(cc * 16 + c, ks * 4 + g));
#pragma unroll
        for (int rf = 0; rf < 2; ++rf)
          Oacc[rf][cc] = __builtin_amdgcn_mfma_f32_16x16x32_bf16(pa[rf], vb, Oacc[rf][cc], 0, 0, 0);
      }
      __builtin_amdgcn_s_setprio(0);
    }
  };

#pragma unroll 1
  for (int t = 0; t < 2; ++t) {
    const int colbase = cbg * 512 + t * 256;
    const bf16* xB = xnb + (size_t)colbase * D_;

    f32x4 Sacc[8][4];
#pragma unroll
    for (int rf = 0; rf < 8; ++rf)
#pragma unroll
      for (int cf = 0; cf < 4; ++cf) Sacc[rf][cf] = zero;

    // prologue = virtual step -1, issue order [B-ch0, A-rh0, B-ch1, A-rh1]
    stageBh(xB, B0, 0, tid);
    stageAh(xA, A0, 0, tid);
    stageBh(xB, B0, 1, tid);
    stageAh(xA, A0, 1, tid);

#pragma unroll 1
    for (int kk = 0; kk < NKK - 1; ++kk) {
      const char* Ac = (kk & 1) ? A1 : A0;
      const char* Bc = (kk & 1) ? B1 : B0;
      char* An = (kk & 1) ? A0 : A1;
      char* Bn = (kk & 1) ? B0 : B1;
      const bf16* sa = xA + (kk + 1) * 64;
      const bf16* sb = xB + (kk + 1) * 64;
      bf16x8 af[4][2], bv[2][2];
      // p0: q(rh0,ch0). needs B-ch0@(kk-1,p0), A-rh0@(kk-1,p1) -> 4 newer pairs allowed
      PH_SYNC(4)
      stageBh(sb, Bn, 0, tid);
      RD_AF(Ac, 0) RD_BV(Bc, 0) QMFMA(0, 0)
      // p1: q(rh0,ch1). needs B-ch1@(kk-1,p2) -> (kk-1,p3),(kk,p0) outstanding
      PH_SYNC(4)
      stageAh(sa, An, 0, tid);
      RD_BV(Bc, 1) QMFMA(0, 1)
      // p2: q(rh1,ch1). needs A-rh1@(kk-1,p3) -> (kk,p0),(kk,p1) outstanding
      PH_SYNC(4)
      stageBh(sb, Bn, 1, tid);
      RD_AF(Ac, 1) QMFMA(1, 1)
      // p3: q(rh1,ch0). nothing new required
      PH_SYNC(6)
      stageAh(sa, An, 1, tid);
      RD_BV(Bc, 0) QMFMA(1, 0)
    }
    {   // peeled kk = 15 (odd): cur = A1/B1, no issues; drain 4/2/0/0
      bf16x8 af[4][2], bv[2][2];
      PH_SYNC(4)
      RD_AF(A1, 0) RD_BV(B1, 0) QMFMA(0, 0)
      PH_SYNC(2)
      RD_BV(B1, 1) QMFMA(0, 1)
      PH_SYNC(0)
      RD_AF(A1, 1) QMFMA(1, 1)
      __builtin_amdgcn_s_barrier();
      __builtin_amdgcn_sched_barrier(0);
      RD_BV(B1, 0) QMFMA(1, 0)
    }
    __syncthreads();                 // seal all kk15 readers; vm = 0

    stageV(yT, colbase, 0, A0, tid); // V-h0 -> A0 (dead since kk14)
    stageV(yT, colbase, 1, B1, tid); // V-h1 -> B1 (sealed above)

    // exp (overlaps V flight): w = exp(-sqrt(max(xsq + xnsq - 2*dot, 0)))
    float4 nsq[4];
#pragma unroll
    for (int cf = 0; cf < 4; ++cf)
      nsq[cf] = *(const float4*)(xnsq + colbase + wc * 64 + cf * 16 + g * 4);
#pragma unroll
    for (int rf = 0; rf < 8; ++rf) {
      const float xsv = xsq[row0 + wr * 128 + rf * 16 + c];
#pragma unroll
      for (int cf = 0; cf < 4; ++cf)
#pragma unroll
        for (int r = 0; r < 4; ++r) {
          float d2 = xsv + ((const float*)&nsq[cf])[r] - 2.0f * Sacc[rf][cf][r];
          d2 = fmaxf(d2, 0.0f);
          const float wv = __expf(-sqrtf(d2));
          lsum[rf] += wv;
          Sacc[rf][cf][r] = wv;
        }
    }

    if (wc < 2) writeP(Sacc);        // P-h0 = xn 0..127 (waves wc 0,1)
    __syncthreads();                 // V landed (vmcnt0), P-h0 visible
    pvHalf(A0);                      // PV half 0
    __syncthreads();                 // P-h0 readers done
    if (wc >= 2) writeP(Sacc);       // P-h1 = xn 128..255
    __syncthreads();                 // P-h1 visible
    pvHalf(B1);                      // PV half 1
    __syncthreads();                 // seal before next tile prologue / Lred
  }

  // ---- L reduce: lanes over g (shfl), waves over wc (LDS) ----
  float* Lr = (float*)Lds;           // [4 wc][256 rows]
#pragma unroll
  for (int rf = 0; rf < 8; ++rf) {
    float v = lsum[rf];
    v += __shfl_xor(v, 16);
    v += __shfl_xor(v, 32);
    if (g == 0) Lr[wc * 256 + wr * 128 + rf * 16 + c] = v;
  }
  __syncthreads();
  if (tid < 256)
    Lpart[(size_t)cbg * N_ + row0 + tid] =
        Lr[tid] + Lr[256 + tid] + Lr[512 + tid] + Lr[768 + tid];

  float* ob = Opart + ((size_t)cbg * N_ + row0) * C_;
#pragma unroll
  for (int rf = 0; rf < 2; ++rf)
#pragma unroll
    for (int cc = 0; cc < 8; ++cc)
#pragma unroll
      for (int r = 0; r < 4; ++r)
        ob[(wave * 32 + rf * 16 + g * 4 + r) * C_ + cc * 16 + c] = Oacc[rf][cc][r];
}

// row-wise: f32 -> bf16 copy + exact f32 squared norm
__global__ void prep_rows(const float* __restrict__ src, bf16* __restrict__ dst,
                          float* __restrict__ sq)
{
  const int row = blockIdx.x;
  const int t = threadIdx.x;                   // 256 threads, 4 f32 each
  const float4 v = reinterpret_cast<const float4*>(src + (size_t)row * D_)[t];
  float ss = v.x * v.x + v.y * v.y + v.z * v.z + v.w * v.w;
  bf16x4 hv;
  hv[0] = (bf16)v.x; hv[1] = (bf16)v.y; hv[2] = (bf16)v.z; hv[3] = (bf16)v.w;
  *reinterpret_cast<bf16x4*>(dst + (size_t)row * D_ + t * 4) = hv;
#pragma unroll
  for (int o = 32; o > 0; o >>= 1) ss += __shfl_down(ss, o);
  __shared__ float red[4];
  if ((t & 63) == 0) red[t >> 6] = ss;
  __syncthreads();
  if (t == 0) sq[row] = red[0] + red[1] + red[2] + red[3];
}

// y[8192][128] f32 -> yT[128][8192] bf16
__global__ void prep_yT(const float* __restrict__ y, bf16* __restrict__ yT)
{
  __shared__ bf16 tile[C_][72];
  const int m0 = blockIdx.x * 64;
  const int t = threadIdx.x;
#pragma unroll
  for (int i = 0; i < 32; ++i) {
    const int idx = i * 256 + t;               // 0..8191
    const int ml = idx >> 7, cc = idx & 127;
    tile[cc][ml] = (bf16)y[(size_t)(m0 + ml) * C_ + cc];
  }
  __syncthreads();
#pragma unroll
  for (int i = 0; i < 32; ++i) {
    const int idx = i * 256 + t;
    const int cc = idx >> 6, ml = idx & 63;
    yT[(size_t)cc * M_ + m0 + ml] = tile[cc][ml];
  }
}

__global__ void lred(const float* __restrict__ Lpart, float* __restrict__ l)
{
  const int row = blockIdx.x * 256 + threadIdx.x;  // < N_
  float s = 0.f;
#pragma unroll
  for (int cb = 0; cb < NCBG; ++cb) s += Lpart[(size_t)cb * N_ + row];
  l[row] = s;
}

__global__ void combine(const float* __restrict__ Opart, const float* __restrict__ l,
                        float* __restrict__ out)
{
  const int i = blockIdx.x * 256 + threadIdx.x;    // < N_*C_
  float o = 0.f;
#pragma unroll
  for (int cb = 0; cb < NCBG; ++cb) o += Opart[(size_t)cb * N_ * C_ + i];
  out[i] = o / l[i >> 7];
}

extern "C" void kernel_launch(void* const* d_in, const int* in_sizes, int n_in,
                              void* d_out, int out_size, void* d_ws, size_t ws_size,
                              hipStream_t stream)
{
  const float* x  = (const float*)d_in[0];
  const float* xn = (const float*)d_in[1];
  const float* y  = (const float*)d_in[2];
  // d_in[3] = log_T: computed-but-unused in the reference forward.
  float* out = (float*)d_out;

  char* ws = (char*)d_ws;
  bf16*  xb    = (bf16*)(ws);
  bf16*  xnb   = (bf16*)(ws + (size_t)8  * 1024 * 1024);
  bf16*  yT    = (bf16*)(ws + (size_t)24 * 1024 * 1024);
  float* xsq   = (float*)(ws + (size_t)26 * 1024 * 1024);
  float* xnsq  = (float*)(ws + (size_t)26 * 1024 * 1024 + 16 * 1024);
  float* l     = (float*)(ws + (size_t)26 * 1024 * 1024 + 48 * 1024);
  float* Lpart = (float*)(ws + (size_t)26 * 1024 * 1024 + 64 * 1024);
  float* Opart = (float*)(ws + (size_t)27 * 1024 * 1024);   // 16 x 2 MiB

  prep_rows<<<N_, 256, 0, stream>>>(x, xb, xsq);
  prep_rows<<<M_, 256, 0, stream>>>(xn, xnb, xnsq);
  prep_yT<<<M_ / 64, 256, 0, stream>>>(y, yT);
  nona_main<<<16 * NCBG, 512, 0, stream>>>(xb, xnb, yT, xsq, xnsq, Opart, Lpart);
  lred<<<N_ / 256, 256, 0, stream>>>(Lpart, l);
  combine<<<(N_ * C_) / 256, 256, 0, stream>>>(Opart, l, out);
}

// Round 9
// 150.916 us; speedup vs baseline: 1.4457x; 1.4457x over previous
//
#include <hip/hip_runtime.h>

// NONA: out = softmax(-cdist(x, x_n), axis=1) @ y
//   x[4096,1024] f32, x_n[8192,1024] f32, y[8192,128] f32, log_T unused.
//
// R9 (model from R5..R8: R5 = 34%-ceiling geometry, 68% LDS-busy + stalls;
// R7/R8 big-tile = 54-73% ceiling but coarse/shallow pipelines stall 4x.
// Fix = big-tile fused + DEPTH-2 prefetch, 1 barrier/K-step):
//  * BM=256 x BN=128 per block, 8 waves = 4(wr: 64 rows) x 2(wc: 64 cols).
//    Sacc[4][4]; O-half per wave Oacc[4][4] (wc splits C) -> no register wall.
//  * LDS triple-buffer: A[256][64] x3 @ 0/32K/64K, B[128][64] x3 @ 96/112/128K
//    = 144K. Stage(kk+2) issued at kk -> ~2 K-steps of load flight.
//    Per step: vmcnt(6); s_barrier; sched_barrier; issue 6 loads; 16 ds_read;
//    32 MFMA (setprio). Tail kk=14 (no issue), kk=15 (vmcnt 0).
//    RAW: own vmcnt(6)+barrier => all waves' stage(kk) landed.
//    WAR: stage(kk+2) hits buf((kk-1)%3); its readers passed this barrier.
//  * bn epilogue: sync; stage V[128C][128]->B0B1; exp (overlaps V flight);
//    P[256][128]->A0A1 (b64, swz2); sync (drains V); PV 64 MFMA/wave; sync.
//  * grid = 16 rb x 16 split = 256 = 1/CU (ws>=93Mi proven R5: Opart 32Mi ok).
//  * prep fused into one kernel; l-reduce fused into combine.
//
// ws: xb@0 8Mi | xnb@8Mi 16Mi | yT@24Mi 2Mi | xsq@26Mi 16Ki | xnsq +16Ki |
//     Lpart@26Mi+64Ki 256Ki | Opart@27Mi 32Mi  (59Mi total)

#define N_ 4096
#define M_ 8192
#define D_ 1024
#define C_ 128
#define SPLIT 16
#define MCOLS (M_ / SPLIT)    // 512
#define NBN (MCOLS / 128)     // 4

typedef __bf16 bf16;
typedef __attribute__((ext_vector_type(8))) __bf16 bf16x8;
typedef __attribute__((ext_vector_type(4))) __bf16 bf16x4;
typedef __attribute__((ext_vector_type(4))) float f32x4;

__device__ __forceinline__ void async_copy16(const bf16* gp, void* lp) {
  __builtin_amdgcn_global_load_lds(
      (__attribute__((address_space(1))) void*)const_cast<bf16*>(gp),
      (__attribute__((address_space(3))) void*)lp, 16, 0, 0);
}

// 128-B-row tiles (A/B): 16B-granule XOR row&7 (0-conflict, R1-R8)
__device__ __forceinline__ int swz(int row, int gran) {
  return (row << 7) + ((gran ^ (row & 7)) << 4);
}
// 256-B-row tiles (P/V): 16 granules, XOR row&15
__device__ __forceinline__ int swz2(int row, int gran) {
  return (row << 8) + ((gran ^ (row & 15)) << 4);
}

// A [256][64] (32K, 32 chunks): 4 loads/thread @512 thr. Source pre-swizzled.
__device__ __forceinline__ void stageA(const bf16* src, char* lds, int tid) {
  const int lane = tid & 63, wave = tid >> 6;
#pragma unroll
  for (int j = 0; j < 4; ++j) {
    const int ch  = j * 8 + wave;
    const int off = ch * 1024 + lane * 16;
    const int row = off >> 7;
    const int gr  = ((off >> 4) & 7) ^ (row & 7);
    async_copy16(src + (size_t)row * D_ + gr * 8, lds + ch * 1024);
  }
}
// B [128][64] (16K, 16 chunks): 2 loads/thread
__device__ __forceinline__ void stageB(const bf16* src, char* lds, int tid) {
  const int lane = tid & 63, wave = tid >> 6;
#pragma unroll
  for (int j = 0; j < 2; ++j) {
    const int ch  = j * 8 + wave;
    const int off = ch * 1024 + lane * 16;
    const int row = off >> 7;
    const int gr  = ((off >> 4) & 7) ^ (row & 7);
    async_copy16(src + (size_t)row * D_ + gr * 8, lds + ch * 1024);
  }
}
// V = yT[128 C][128 xn] (32K, 256-B rows): 4 loads/thread
__device__ __forceinline__ void stageV(const bf16* yT, int colbase, char* lds, int tid) {
  const int lane = tid & 63, wave = tid >> 6;
#pragma unroll
  for (int j = 0; j < 4; ++j) {
    const int ch  = j * 8 + wave;
    const int off = ch * 1024 + lane * 16;
    const int row = off >> 8;
    const int gr  = ((off >> 4) & 15) ^ (row & 15);
    async_copy16(yT + (size_t)row * M_ + colbase + gr * 8, lds + ch * 1024);
  }
}

// One K-step: wait own stage(kk); barrier; pin; issue stage(kk+2); read+MFMA.
#define KSTEP(Ac, Bc, DOSTG, KKP2, An, Bn, VM)                                 \
  asm volatile("s_waitcnt vmcnt(" #VM ")" ::: "memory");                       \
  __builtin_amdgcn_s_barrier();                                                \
  __builtin_amdgcn_sched_barrier(0);                                           \
  if (DOSTG) { stageA(xA + (KKP2) * 64, An, tid);                              \
               stageB(xB + (KKP2) * 64, Bn, tid); }                            \
  {                                                                            \
    _Pragma("unroll") for (int ks = 0; ks < 2; ++ks) {                         \
      bf16x8 af[4], bv[4];                                                     \
      _Pragma("unroll") for (int i = 0; i < 4; ++i)                            \
        af[i] = *(const bf16x8*)((Ac) + swz(wr * 64 + i * 16 + c, ks * 4 + g));\
      _Pragma("unroll") for (int j = 0; j < 4; ++j)                            \
        bv[j] = *(const bf16x8*)((Bc) + swz(wc * 64 + j * 16 + c, ks * 4 + g));\
      __builtin_amdgcn_s_setprio(1);                                           \
      _Pragma("unroll") for (int j = 0; j < 4; ++j)                            \
      _Pragma("unroll") for (int i = 0; i < 4; ++i)                            \
        Sacc[i][j] = __builtin_amdgcn_mfma_f32_16x16x32_bf16(                  \
            bv[j], af[i], Sacc[i][j], 0, 0, 0);                                \
      __builtin_amdgcn_s_setprio(0);                                           \
    }                                                                          \
  }

__global__ __launch_bounds__(512, 1)
void nona_main(const bf16* __restrict__ xb, const bf16* __restrict__ xnb,
               const bf16* __restrict__ yT, const float* __restrict__ xsq,
               const float* __restrict__ xnsq, float* __restrict__ Opart,
               float* __restrict__ Lpart)
{
  __shared__ __align__(16) char Lds[147456];
  char* const A0 = Lds;             // kk%3==0 x-buf; tail: P rows (A0+A1, 64K)
  char* const A1 = Lds + 32768;
  char* const A2 = Lds + 65536;
  char* const B0 = Lds + 98304;     // kk%3==0 xn-buf; tail: V (B0+B1, 32K)
  char* const B1 = Lds + 114688;
  char* const B2 = Lds + 131072;
  char* const Pb = A0;              // P [256][128] bf16, 256-B rows
  char* const Vb = B0;              // V [128 C][128 xn]

  const int tid  = threadIdx.x;
  const int lane = tid & 63;
  const int wave = tid >> 6;           // 8 waves: wr = wave&3 (64 rows), wc = wave>>2
  const int wr = wave & 3, wc = wave >> 2;
  const int g = lane >> 4, c = lane & 15;

  const int s    = blockIdx.x & 15;    // split id; bid%8 -> XCD locality
  const int rb   = blockIdx.x >> 4;
  const int row0 = rb * 256;
  const int col0 = s * MCOLS;

  const bf16* xA = xb + (size_t)row0 * D_;

  float xs[4];
#pragma unroll
  for (int rf = 0; rf < 4; ++rf)
    xs[rf] = xsq[row0 + wr * 64 + rf * 16 + c];

  f32x4 Oacc[4][4];
  const f32x4 zero = {0.f, 0.f, 0.f, 0.f};
#pragma unroll
  for (int rf = 0; rf < 4; ++rf)
#pragma unroll
    for (int cc = 0; cc < 4; ++cc) Oacc[rf][cc] = zero;
  float lsum[4] = {0.f, 0.f, 0.f, 0.f};

#pragma unroll 1
  for (int bn = 0; bn < NBN; ++bn) {
    const int colbase = col0 + bn * 128;
    const bf16* xB = xnb + (size_t)colbase * D_;

    f32x4 Sacc[4][4];
#pragma unroll
    for (int rf = 0; rf < 4; ++rf)
#pragma unroll
      for (int cf = 0; cf < 4; ++cf) Sacc[rf][cf] = zero;

    // prologue (prev bn sealed by post-PV syncthreads): stage kk=0,1
    stageA(xA, A0, tid);          stageB(xB, B0, tid);
    stageA(xA + 64, A1, tid);     stageB(xB + 64, B1, tid);

#pragma unroll 1
    for (int t = 0; t < 4; ++t) {        // kk = 3t, 3t+1, 3t+2  (0..11)
      const int kk = 3 * t;
      KSTEP(A0, B0, 1, kk + 2, A2, B2, 6)
      KSTEP(A1, B1, 1, kk + 3, A0, B0, 6)
      KSTEP(A2, B2, 1, kk + 4, A1, B1, 6)
    }
    KSTEP(A0, B0, 1, 14, A2, B2, 6)      // kk=12
    KSTEP(A1, B1, 1, 15, A0, B0, 6)      // kk=13
    KSTEP(A2, B2, 0, 0, A0, B0, 6)       // kk=14
    KSTEP(A0, B0, 0, 0, A0, B0, 0)       // kk=15
    __syncthreads();                     // seal kk15 readers (A0/B0) for P/V reuse

    stageV(yT, colbase, Vb, tid);        // V -> B0+B1 (in flight under exp)

    // exp: w = exp(-sqrt(max(xsq + xnsq - 2*dot, 0))); lane holds
    // S[xn = wc*64 + cf*16 + g*4 + r][xrow = wr*64 + rf*16 + c]
#pragma unroll
    for (int cf = 0; cf < 4; ++cf) {
      const float4 nsq4 = *(const float4*)(xnsq + colbase + wc * 64 + cf * 16 + g * 4);
#pragma unroll
      for (int rf = 0; rf < 4; ++rf)
#pragma unroll
        for (int r = 0; r < 4; ++r) {
          float d2 = xs[rf] + ((const float*)&nsq4)[r] - 2.0f * Sacc[rf][cf][r];
          d2 = fmaxf(d2, 0.0f);
          const float wv = __expf(-sqrtf(d2));
          lsum[rf] += wv;
          Sacc[rf][cf][r] = wv;
        }
    }

    // P-write -> A0+A1 [256 xrow][128 xn], b64 per (rf,cf)
#pragma unroll
    for (int rf = 0; rf < 4; ++rf)
#pragma unroll
      for (int cf = 0; cf < 4; ++cf) {
        bf16x4 pk;
#pragma unroll
        for (int r = 0; r < 4; ++r) pk[r] = (bf16)Sacc[rf][cf][r];
        const int row  = wr * 64 + rf * 16 + c;
        const int gran = wc * 8 + cf * 2 + (g >> 1);
        *(bf16x4*)(Pb + (row << 8) + ((gran ^ (row & 15)) << 4) + (g & 1) * 8) = pk;
      }
    __syncthreads();                     // V landed (vmcnt0 drain); P visible

    // PV: O[64 rows x 64 C-half] += P[64 x 128] @ V^T
#pragma unroll
    for (int ks = 0; ks < 4; ++ks) {
      bf16x8 pa[4];
#pragma unroll
      for (int rf = 0; rf < 4; ++rf)
        pa[rf] = *(const bf16x8*)(Pb + swz2(wr * 64 + rf * 16 + c, ks * 4 + g));
      __builtin_amdgcn_s_setprio(1);
#pragma unroll
      for (int cc = 0; cc < 4; ++cc) {
        bf16x8 vb = *(const bf16x8*)(Vb + swz2(wc * 64 + cc * 16 + c, ks * 4 + g));
#pragma unroll
        for (int rf = 0; rf < 4; ++rf)
          Oacc[rf][cc] = __builtin_amdgcn_mfma_f32_16x16x32_bf16(pa[rf], vb, Oacc[rf][cc], 0, 0, 0);
      }
      __builtin_amdgcn_s_setprio(0);
    }
    __syncthreads();                     // seal P/V readers before next bn restage
  }

  // ---- L reduce: over g (shfl), then over wc (LDS) ----
  float* Lr = (float*)Lds;               // [2 wc][256 rows]
#pragma unroll
  for (int rf = 0; rf < 4; ++rf) {
    float v = lsum[rf];
    v += __shfl_xor(v, 16);
    v += __shfl_xor(v, 32);
    if (g == 0) Lr[wc * 256 + wr * 64 + rf * 16 + c] = v;
  }
  __syncthreads();
  if (tid < 256)
    Lpart[(size_t)s * N_ + row0 + tid] = Lr[tid] + Lr[256 + tid];

  float* ob = Opart + ((size_t)s * N_ + row0) * C_;
#pragma unroll
  for (int rf = 0; rf < 4; ++rf)
#pragma unroll
    for (int cc = 0; cc < 4; ++cc)
#pragma unroll
      for (int r = 0; r < 4; ++r)
        ob[(wr * 64 + rf * 16 + g * 4 + r) * C_ + wc * 64 + cc * 16 + c] = Oacc[rf][cc][r];
}

// fused prep: rows [0,N) = x -> xb/xsq; rows [N, N+M) = xn -> xnb/xnsq
__global__ void prep_rows(const float* __restrict__ x, const float* __restrict__ xn,
                          bf16* __restrict__ xb, bf16* __restrict__ xnb,
                          float* __restrict__ xsq, float* __restrict__ xnsq)
{
  const int blk = blockIdx.x;
  const float* src; bf16* dst; float* sq; int row;
  if (blk < N_) { src = x;  dst = xb;  sq = xsq;  row = blk; }
  else          { src = xn; dst = xnb; sq = xnsq; row = blk - N_; }
  const int t = threadIdx.x;                   // 256 threads, 4 f32 each
  const float4 v = reinterpret_cast<const float4*>(src + (size_t)row * D_)[t];
  float ss = v.x * v.x + v.y * v.y + v.z * v.z + v.w * v.w;
  bf16x4 hv;
  hv[0] = (bf16)v.x; hv[1] = (bf16)v.y; hv[2] = (bf16)v.z; hv[3] = (bf16)v.w;
  *reinterpret_cast<bf16x4*>(dst + (size_t)row * D_ + t * 4) = hv;
#pragma unroll
  for (int o = 32; o > 0; o >>= 1) ss += __shfl_down(ss, o);
  __shared__ float red[4];
  if ((t & 63) == 0) red[t >> 6] = ss;
  __syncthreads();
  if (t == 0) sq[row] = red[0] + red[1] + red[2] + red[3];
}

// y[8192][128] f32 -> yT[128][8192] bf16
__global__ void prep_yT(const float* __restrict__ y, bf16* __restrict__ yT)
{
  __shared__ bf16 tile[C_][72];
  const int m0 = blockIdx.x * 64;
  const int t = threadIdx.x;
#pragma unroll
  for (int i = 0; i < 32; ++i) {
    const int idx = i * 256 + t;               // 0..8191
    const int ml = idx >> 7, cc = idx & 127;
    tile[cc][ml] = (bf16)y[(size_t)(m0 + ml) * C_ + cc];
  }
  __syncthreads();
#pragma unroll
  for (int i = 0; i < 32; ++i) {
    const int idx = i * 256 + t;
    const int cc = idx >> 6, ml = idx & 63;
    yT[(size_t)cc * M_ + m0 + ml] = tile[cc][ml];
  }
}

__global__ void combine(const float* __restrict__ Opart, const float* __restrict__ Lpart,
                        float* __restrict__ out)
{
  const int i = blockIdx.x * 256 + threadIdx.x;   // < N_*C_
  const int row = i >> 7;
  float o = 0.f, l = 0.f;
#pragma unroll
  for (int s = 0; s < SPLIT; ++s) {
    o += Opart[(size_t)s * N_ * C_ + i];
    l += Lpart[(size_t)s * N_ + row];
  }
  out[i] = o / l;
}

extern "C" void kernel_launch(void* const* d_in, const int* in_sizes, int n_in,
                              void* d_out, int out_size, void* d_ws, size_t ws_size,
                              hipStream_t stream)
{
  const float* x  = (const float*)d_in[0];
  const float* xn = (const float*)d_in[1];
  const float* y  = (const float*)d_in[2];
  // d_in[3] = log_T: computed-but-unused in the reference forward.
  float* out = (float*)d_out;

  char* ws = (char*)d_ws;
  bf16*  xb    = (bf16*)(ws);
  bf16*  xnb   = (bf16*)(ws + (size_t)8  * 1024 * 1024);
  bf16*  yT    = (bf16*)(ws + (size_t)24 * 1024 * 1024);
  float* xsq   = (float*)(ws + (size_t)26 * 1024 * 1024);
  float* xnsq  = (float*)(ws + (size_t)26 * 1024 * 1024 + 16 * 1024);
  float* Lpart = (float*)(ws + (size_t)26 * 1024 * 1024 + 64 * 1024);
  float* Opart = (float*)(ws + (size_t)27 * 1024 * 1024);   // 16 x 2 MiB

  prep_rows<<<N_ + M_, 256, 0, stream>>>(x, xn, xb, xnb, xsq, xnsq);
  prep_yT<<<M_ / 64, 256, 0, stream>>>(y, yT);
  nona_main<<<16 * SPLIT, 512, 0, stream>>>(xb, xnb, yT, xsq, xnsq, Opart, Lpart);
  combine<<<(N_ * C_) / 256, 256, 0, stream>>>(Opart, Lpart, out);
}